// Round 3
// baseline (861.706 us; speedup 1.0000x reference)
//
#include <hip/hip_runtime.h>
#include <stdint.h>

typedef _Float16 f16;
typedef _Float16 f16x4 __attribute__((ext_vector_type(4)));
typedef _Float16 f16x8 __attribute__((ext_vector_type(8)));
typedef float    f32x4 __attribute__((ext_vector_type(4)));

#define LO_SCALE 2048.0f
#define LO_INV   (1.0f / 2048.0f)

__device__ __forceinline__ void llds16(const void* g, void* l) {
    __builtin_amdgcn_global_load_lds(
        (const __attribute__((address_space(1))) void*)g,
        (__attribute__((address_space(3))) void*)l, 16, 0, 0);
}

__device__ __forceinline__ unsigned long long pack_key(float s, int j) {
    unsigned u = __float_as_uint(s);
    u = (u & 0x80000000u) ? ~u : (u | 0x80000000u);
    return ((unsigned long long)u << 32) | (unsigned)(~(unsigned)j);
}

// ---------------- convert emb -> hi/lo fp16 + rinv ----------------
__global__ void convert_emb_kernel(const float* __restrict__ emb,
                                   f16* __restrict__ bh, f16* __restrict__ bl,
                                   float* __restrict__ rinv, int V, int E) {
    int row  = blockIdx.x * (blockDim.x >> 6) + (threadIdx.x >> 6);
    int lane = threadIdx.x & 63;
    if (row >= V) return;
    const float4* p = (const float4*)(emb + (size_t)row * E);
    int n4 = E >> 2;
    float ss = 0.f;
    for (int i = lane; i < n4; i += 64) {
        float4 v = p[i];
        ss = fmaf(v.x, v.x, ss); ss = fmaf(v.y, v.y, ss);
        ss = fmaf(v.z, v.z, ss); ss = fmaf(v.w, v.w, ss);
    }
    #pragma unroll
    for (int o = 32; o > 0; o >>= 1) ss += __shfl_down(ss, o, 64);
    if (lane == 0) rinv[row] = 1.0f / sqrtf(ss);

    for (int i = lane; i < n4; i += 64) {
        float4 v = p[i];
        f16x4 h, l;
        h.x = (f16)v.x; l.x = (f16)((v.x - (float)h.x) * LO_SCALE);
        h.y = (f16)v.y; l.y = (f16)((v.y - (float)h.y) * LO_SCALE);
        h.z = (f16)v.z; l.z = (f16)((v.z - (float)h.z) * LO_SCALE);
        h.w = (f16)v.w; l.w = (f16)((v.w - (float)h.w) * LO_SCALE);
        *(f16x4*)&bh[(size_t)row * E + i * 4] = h;
        *(f16x4*)&bl[(size_t)row * E + i * 4] = l;
    }
}

// ---------------- convert batch -> hi/lo fp16 ----------------
__global__ void convert_batch_kernel(const float* __restrict__ batch,
                                     f16* __restrict__ ah, f16* __restrict__ al,
                                     int M, int E) {
    int row  = blockIdx.x * (blockDim.x >> 6) + (threadIdx.x >> 6);
    int lane = threadIdx.x & 63;
    if (row >= M) return;
    const float4* p = (const float4*)(batch + (size_t)row * E);
    int n4 = E >> 2;
    for (int i = lane; i < n4; i += 64) {
        float4 v = p[i];
        f16x4 h, l;
        h.x = (f16)v.x; l.x = (f16)((v.x - (float)h.x) * LO_SCALE);
        h.y = (f16)v.y; l.y = (f16)((v.y - (float)h.y) * LO_SCALE);
        h.z = (f16)v.z; l.z = (f16)((v.z - (float)h.z) * LO_SCALE);
        h.w = (f16)v.w; l.w = (f16)((v.w - (float)h.w) * LO_SCALE);
        *(f16x4*)&ah[(size_t)row * E + i * 4] = h;
        *(f16x4*)&al[(size_t)row * E + i * 4] = l;
    }
}

// ---------------- init packed keys ----------------
__global__ void init_keys_kernel(unsigned long long* __restrict__ keys, int M) {
    int i = blockIdx.x * blockDim.x + threadIdx.x;
    if (i < M) keys[i] = 0ULL;
}

// ---------------- phase-pipelined MFMA GEMM + fused argmax ----------------
#define BM 256
#define BN 128
#define BKH 32                 // K halfs per tile
#define TILE_BYTES 49152       // 48 KB per buffer
#define AH_OFF 0               // 256*32*2 = 16 KB
#define AL_OFF 16384
#define BH_OFF 32768           // 128*32*2 = 8 KB
#define BL_OFF 40960

__global__ __launch_bounds__(512, 2) void nn_mfma8(
    const f16* __restrict__ Ah, const f16* __restrict__ Al,
    const f16* __restrict__ Bh, const f16* __restrict__ Bl,
    const float* __restrict__ rinv, unsigned long long* __restrict__ keys,
    int M, int V, int E)
{
    extern __shared__ char smem[];

    const int tid  = threadIdx.x;
    const int lane = tid & 63;
    const int w    = tid >> 6;        // wave 0..7
    const int wr   = w >> 1;          // 0..3 (64 M-rows each)
    const int wc   = w & 1;           // 0..1 (64 N-cols each)
    const int fr   = lane & 15;
    const int kg   = lane >> 4;       // 0..3

    // ---- block decode with bijective XCD swizzle (nwg % 8 == 0) ----
    int nwg = gridDim.x;
    int bid = blockIdx.x;
    int swz = ((nwg & 7) == 0) ? ((bid & 7) * (nwg >> 3) + (bid >> 3)) : bid;
    const int mblocks = M / BM;
    const int mb = swz % mblocks;     // consecutive blocks share the B panel
    const int nb = swz / mblocks;
    const int row0 = mb * BM;
    const int col0 = nb * BN;

    // ---- staging addressing: 6 global_load_lds per thread per tile ----
    // each issue: 64 lanes x 16B = 16 rows of 64B; lane -> (row lane>>2, slot lane&3)
    const int r4 = lane >> 2;
    const int sl = lane & 3;
    const int arow0 = w * 32 + r4;          // tile-A row for issue 0/2
    const int arow1 = arow0 + 16;           // issue 1/3
    const int brow  = w * 16 + r4;          // tile-B row for issue 4/5
    const int aslot0 = sl ^ ((arow0 >> 1) & 3);   // pre-swizzled source slot
    const int aslot1 = sl ^ ((arow1 >> 1) & 3);
    const int bslot  = sl ^ ((brow  >> 1) & 3);
    int bj = col0 + brow; if (bj > V - 1) bj = V - 1;

    const f16* gA0 = Ah + (size_t)(row0 + arow0) * E + aslot0 * 8;
    const f16* gA1 = Ah + (size_t)(row0 + arow1) * E + aslot1 * 8;
    const f16* gA2 = Al + (size_t)(row0 + arow0) * E + aslot0 * 8;
    const f16* gA3 = Al + (size_t)(row0 + arow1) * E + aslot1 * 8;
    const f16* gB0 = Bh + (size_t)bj * E + bslot * 8;
    const f16* gB1 = Bl + (size_t)bj * E + bslot * 8;

    const int ldsA0 = AH_OFF + (w * 32)      * 64;
    const int ldsA1 = AH_OFF + (w * 32 + 16) * 64;
    const int ldsA2 = AL_OFF + (w * 32)      * 64;
    const int ldsA3 = AL_OFF + (w * 32 + 16) * 64;
    const int ldsB0 = BH_OFF + (w * 16)      * 64;
    const int ldsB1 = BL_OFF + (w * 16)      * 64;

    // ---- fragment read offsets (bytes within a buffer), swizzled read ----
    int aoffs[4], boffs[4];
    #pragma unroll
    for (int m = 0; m < 4; ++m) {
        int row  = wr * 64 + m * 16 + fr;
        int slot = kg ^ ((row >> 1) & 3);
        aoffs[m] = row * 64 + slot * 16;
    }
    #pragma unroll
    for (int n = 0; n < 4; ++n) {
        int col  = wc * 64 + n * 16 + fr;
        int slot = kg ^ ((col >> 1) & 3);
        boffs[n] = col * 64 + slot * 16;
    }

    f32x4 acc[4][4], accx[4][4];
    #pragma unroll
    for (int m = 0; m < 4; ++m)
        #pragma unroll
        for (int n = 0; n < 4; ++n) {
            acc[m][n]  = (f32x4){0.f, 0.f, 0.f, 0.f};
            accx[m][n] = (f32x4){0.f, 0.f, 0.f, 0.f};
        }

    const int steps = E / BKH;   // 16

    auto STAGE = [&](int bufp, int tk, int phase) {
        const size_t kb = (size_t)tk * BKH;   // advance in halfs
        char* base = smem + bufp * TILE_BYTES;
        if (phase == 0) {
            llds16(gA0 + kb, base + ldsA0);
            llds16(gA1 + kb, base + ldsA1);
        } else if (phase == 1) {
            llds16(gA2 + kb, base + ldsA2);
            llds16(gA3 + kb, base + ldsA3);
        } else if (phase == 2) {
            llds16(gB0 + kb, base + ldsB0);
        } else {
            llds16(gB1 + kb, base + ldsB1);
        }
    };

    // ---- prologue: tiles 0 and 1 in flight; wait tile 0 only ----
    #pragma unroll
    for (int q = 0; q < 4; ++q) STAGE(0, 0, q);
    #pragma unroll
    for (int q = 0; q < 4; ++q) STAGE(1, 1, q);
    asm volatile("s_waitcnt vmcnt(6)" ::: "memory");
    __builtin_amdgcn_s_barrier();

    int cur = 0;
    #pragma unroll 1
    for (int t = 0; t < steps; ++t) {
        char* cb = smem + cur * TILE_BYTES;
        int nb2 = cur + 2; if (nb2 >= 3) nb2 -= 3;
        const bool pre = (t + 2 < steps);

        f16x8 ah[4], al[4];
        #pragma unroll
        for (int m = 0; m < 4; ++m) {
            ah[m] = *(const f16x8*)(cb + AH_OFF + aoffs[m]);
            al[m] = *(const f16x8*)(cb + AL_OFF + aoffs[m]);
        }

        #pragma unroll
        for (int q = 0; q < 4; ++q) {
            f16x8 bh = *(const f16x8*)(cb + BH_OFF + boffs[q]);
            f16x8 bl = *(const f16x8*)(cb + BL_OFF + boffs[q]);
            if (pre) STAGE(nb2, t + 2, q);
            asm volatile("s_waitcnt lgkmcnt(0)" ::: "memory");
            __builtin_amdgcn_sched_barrier(0);
            __builtin_amdgcn_s_setprio(1);
            #pragma unroll
            for (int m = 0; m < 4; ++m) {
                acc[m][q]  = __builtin_amdgcn_mfma_f32_16x16x32_f16(ah[m], bh, acc[m][q],  0, 0, 0);
                accx[m][q] = __builtin_amdgcn_mfma_f32_16x16x32_f16(ah[m], bl, accx[m][q], 0, 0, 0);
                accx[m][q] = __builtin_amdgcn_mfma_f32_16x16x32_f16(al[m], bh, accx[m][q], 0, 0, 0);
            }
            __builtin_amdgcn_s_setprio(0);
            if (q == 3) {
                if (pre)                    asm volatile("s_waitcnt vmcnt(6)" ::: "memory");
                else if (t + 1 < steps)     asm volatile("s_waitcnt vmcnt(0)" ::: "memory");
            }
            __builtin_amdgcn_s_barrier();
        }
        cur = cur + 1; if (cur == 3) cur = 0;
    }

    // ---- epilogue: score = (hh + cross/2048) * rinv[j]; fused argmax ----
    const int colb = col0 + wc * 64;
    float ri[4];
    #pragma unroll
    for (int n = 0; n < 4; ++n) {
        int j = colb + n * 16 + fr;
        ri[n] = (j < V) ? rinv[j] : 0.f;
    }
    #pragma unroll
    for (int m = 0; m < 4; ++m) {
        #pragma unroll
        for (int r = 0; r < 4; ++r) {
            unsigned long long best = 0ULL;
            #pragma unroll
            for (int n = 0; n < 4; ++n) {
                int j = colb + n * 16 + fr;
                if (j < V) {
                    float s = (acc[m][n][r] + accx[m][n][r] * LO_INV) * ri[n];
                    unsigned long long key = pack_key(s, j);
                    if (key > best) best = key;
                }
            }
            #pragma unroll
            for (int o = 8; o > 0; o >>= 1) {
                unsigned long long other = __shfl_xor(best, o, 64);
                if (other > best) best = other;
            }
            if (fr == 0 && best != 0ULL) {
                int row = row0 + wr * 64 + m * 16 + kg * 4 + r;
                atomicMax(&keys[row], best);
            }
        }
    }
}

// ---------------- extract indices ----------------
__global__ void extract_kernel(const unsigned long long* __restrict__ keys,
                               int* __restrict__ out, int M) {
    int i = blockIdx.x * blockDim.x + threadIdx.x;
    if (i < M) out[i] = (int)(~(unsigned)(keys[i] & 0xFFFFFFFFULL));
}

// ================= fallback fp32 path (round-0, validated) =================
__global__ void inv_norms_kernel(const float* __restrict__ emb,
                                 float* __restrict__ r, int V, int E) {
    int row  = blockIdx.x * (blockDim.x >> 6) + (threadIdx.x >> 6);
    int lane = threadIdx.x & 63;
    if (row >= V) return;
    const float4* p = reinterpret_cast<const float4*>(emb + (size_t)row * E);
    float ss = 0.f;
    int n4 = E >> 2;
    for (int i = lane; i < n4; i += 64) {
        float4 v = p[i];
        ss = fmaf(v.x, v.x, ss); ss = fmaf(v.y, v.y, ss);
        ss = fmaf(v.z, v.z, ss); ss = fmaf(v.w, v.w, ss);
    }
    #pragma unroll
    for (int o = 32; o > 0; o >>= 1) ss += __shfl_down(ss, o, 64);
    if (lane == 0) r[row] = 1.0f / sqrtf(ss);
}

#define FBM 128
#define FBN 128
#define FBK 32
#define LDSPAD 4

__global__ __launch_bounds__(256) void nn_gemm_argmax(
    const float* __restrict__ batch, const float* __restrict__ emb,
    const float* __restrict__ rinv, unsigned long long* __restrict__ keys,
    int M, int V, int E)
{
    __shared__ float As[FBK][FBM + LDSPAD];
    __shared__ float Bs[FBK][FBN + LDSPAD];
    const int tid = threadIdx.x;
    const int tx  = tid & 15;
    const int ty  = tid >> 4;
    const int row0 = blockIdx.y * FBM;
    const int col0 = blockIdx.x * FBN;
    float acc[8][8];
    #pragma unroll
    for (int i = 0; i < 8; ++i)
        #pragma unroll
        for (int j = 0; j < 8; ++j) acc[i][j] = 0.f;
    const int steps = E / FBK;
    for (int ks = 0; ks < steps; ++ks) {
        const int k0 = ks * FBK;
        #pragma unroll
        for (int it = 0; it < 4; ++it) {
            int idx = it * 256 + tid;
            int rr = idx >> 3, cc = idx & 7;
            float4 v = *reinterpret_cast<const float4*>(
                &batch[(size_t)(row0 + rr) * E + k0 + cc * 4]);
            As[cc*4+0][rr] = v.x; As[cc*4+1][rr] = v.y;
            As[cc*4+2][rr] = v.z; As[cc*4+3][rr] = v.w;
        }
        #pragma unroll
        for (int it = 0; it < 4; ++it) {
            int idx = it * 256 + tid;
            int rr = idx >> 3, cc = idx & 7;
            int j = col0 + rr;
            float4 v = make_float4(0.f,0.f,0.f,0.f);
            if (j < V)
                v = *reinterpret_cast<const float4*>(&emb[(size_t)j * E + k0 + cc * 4]);
            Bs[cc*4+0][rr] = v.x; Bs[cc*4+1][rr] = v.y;
            Bs[cc*4+2][rr] = v.z; Bs[cc*4+3][rr] = v.w;
        }
        __syncthreads();
        #pragma unroll
        for (int k = 0; k < FBK; ++k) {
            float4 a0 = *reinterpret_cast<const float4*>(&As[k][ty*8]);
            float4 a1 = *reinterpret_cast<const float4*>(&As[k][ty*8+4]);
            float4 b0 = *reinterpret_cast<const float4*>(&Bs[k][tx*8]);
            float4 b1 = *reinterpret_cast<const float4*>(&Bs[k][tx*8+4]);
            float a[8] = {a0.x,a0.y,a0.z,a0.w,a1.x,a1.y,a1.z,a1.w};
            float b[8] = {b0.x,b0.y,b0.z,b0.w,b1.x,b1.y,b1.z,b1.w};
            #pragma unroll
            for (int i = 0; i < 8; ++i)
                #pragma unroll
                for (int jj = 0; jj < 8; ++jj)
                    acc[i][jj] = fmaf(a[i], b[jj], acc[i][jj]);
        }
        __syncthreads();
    }
    #pragma unroll
    for (int i = 0; i < 8; ++i) {
        const int q = row0 + ty * 8 + i;
        unsigned long long best = 0ULL;
        #pragma unroll
        for (int jj = 0; jj < 8; ++jj) {
            int j = col0 + tx * 8 + jj;
            if (j < V) {
                unsigned long long key = pack_key(acc[i][jj] * rinv[j], j);
                if (key > best) best = key;
            }
        }
        #pragma unroll
        for (int o = 8; o > 0; o >>= 1) {
            unsigned long long other = __shfl_xor(best, o, 64);
            if (other > best) best = other;
        }
        if (tx == 0 && best != 0ULL) atomicMax(&keys[q], best);
    }
}

// ================= launch =================
extern "C" void kernel_launch(void* const* d_in, const int* in_sizes, int n_in,
                              void* d_out, int out_size, void* d_ws, size_t ws_size,
                              hipStream_t stream) {
    const float* batch = (const float*)d_in[0];  // [B,S,E] f32
    const float* emb   = (const float*)d_in[1];  // [V,E]   f32
    int* out = (int*)d_out;

    const int M = out_size;                 // 4096
    const int E = in_sizes[0] / M;          // 512
    const int V = in_sizes[1] / E;          // 50000

    auto al256 = [](size_t x) { return (x + 255) & ~(size_t)255; };
    size_t o_rinv = 0;
    size_t o_keys = al256(o_rinv + (size_t)V * 4);
    size_t o_Ah   = al256(o_keys + (size_t)M * 8);
    size_t o_Al   = al256(o_Ah + (size_t)M * E * 2);
    size_t o_Bh   = al256(o_Al + (size_t)M * E * 2);
    size_t o_Bl   = al256(o_Bh + (size_t)V * E * 2);
    size_t need   = al256(o_Bl + (size_t)V * E * 2);

    unsigned long long* keys = (unsigned long long*)((char*)d_ws + o_keys);
    float* rinv = (float*)((char*)d_ws + o_rinv);

    if (ws_size >= need && (E % BKH) == 0 && (M % BM) == 0 && (E % 4) == 0) {
        f16* Ah = (f16*)((char*)d_ws + o_Ah);
        f16* Al = (f16*)((char*)d_ws + o_Al);
        f16* Bh = (f16*)((char*)d_ws + o_Bh);
        f16* Bl = (f16*)((char*)d_ws + o_Bl);

        convert_emb_kernel<<<(V + 3) / 4, 256, 0, stream>>>(emb, Bh, Bl, rinv, V, E);
        convert_batch_kernel<<<(M + 3) / 4, 256, 0, stream>>>(batch, Ah, Al, M, E);
        init_keys_kernel<<<(M + 255) / 256, 256, 0, stream>>>(keys, M);

        static int attr_done = 0;  // idempotent host-side attribute set (not a stream op)
        hipFuncSetAttribute((const void*)nn_mfma8,
                            hipFuncAttributeMaxDynamicSharedMemorySize, 3 * TILE_BYTES);
        (void)attr_done;

        int nblocks = (M / BM) * ((V + BN - 1) / BN);   // 16 * 391 = 6256
        nn_mfma8<<<nblocks, 512, 3 * TILE_BYTES, stream>>>(Ah, Al, Bh, Bl, rinv, keys, M, V, E);

        extract_kernel<<<(M + 255) / 256, 256, 0, stream>>>(keys, out, M);
    } else {
        inv_norms_kernel<<<(V + 3) / 4, 256, 0, stream>>>(emb, rinv, V, E);
        init_keys_kernel<<<(M + 255) / 256, 256, 0, stream>>>(keys, M);
        dim3 grid((V + FBN - 1) / FBN, M / FBM);
        nn_gemm_argmax<<<grid, 256, 0, stream>>>(batch, emb, rinv, keys, M, V, E);
        extract_kernel<<<(M + 255) / 256, 256, 0, stream>>>(keys, out, M);
    }
}